// Round 1
// baseline (31.674 us; speedup 1.0000x reference)
//
#include <hip/hip_runtime.h>
#include <math.h>

// y[k] = Re( phase * z_c^k ),  z_c = z * tanh(|z|)/|z|
//      = r^k * (ph_re*cos(k*theta) - ph_im*sin(k*theta)),
//   r = tanh(|z|), theta = atan2(z_im, z_re).
// r^k underflows f32 by k~330 -> tail is zeros; skip transcendentals there.

__global__ void __launch_bounds__(256)
osc_kernel(const float* __restrict__ z_re_p, const float* __restrict__ z_im_p,
           const float* __restrict__ ph_re_p, const float* __restrict__ ph_im_p,
           float* __restrict__ out, int N) {
    const float zr = *z_re_p;
    const float zi = *z_im_p;
    const float pr = *ph_re_p;
    const float pi = *ph_im_p;

    const float mag   = sqrtf(zr * zr + zi * zi);
    const float r     = tanhf(mag);          // constrained magnitude
    const float theta = atan2f(zi, zr);      // angle unchanged by constraint
    const float lr    = logf(r);             // < 0 for r < 1

    // Each thread handles 4 consecutive floats (one float4 store).
    long long base = ((long long)blockIdx.x * blockDim.x + threadIdx.x) * 4;
    if (base >= (long long)N) return;

    if (base + 4 <= (long long)N) {
        float4 v;
        float* pv = &v.x;
#pragma unroll
        for (int j = 0; j < 4; ++j) {
            const float k = (float)(base + j);
            const float e = k * lr;           // log-magnitude of r^k
            if (e < -90.0f) {                 // exp(-90) ~ 8e-40: ref is (de)normal-zero
                pv[j] = 0.0f;
            } else {
                const float rk = expf(e);
                float s, c;
                sincosf(k * theta, &s, &c);
                pv[j] = rk * (pr * c - pi * s);
            }
        }
        *reinterpret_cast<float4*>(out + base) = v;
    } else {
        for (long long idx = base; idx < (long long)N; ++idx) {
            const float k = (float)idx;
            const float e = k * lr;
            if (e < -90.0f) {
                out[idx] = 0.0f;
            } else {
                const float rk = expf(e);
                float s, c;
                sincosf(k * theta, &s, &c);
                out[idx] = rk * (pr * c - pi * s);
            }
        }
    }
}

extern "C" void kernel_launch(void* const* d_in, const int* in_sizes, int n_in,
                              void* d_out, int out_size, void* d_ws, size_t ws_size,
                              hipStream_t stream) {
    const float* z_re = (const float*)d_in[0];
    const float* z_im = (const float*)d_in[1];
    const float* ph_re = (const float*)d_in[2];
    const float* ph_im = (const float*)d_in[3];
    float* out = (float*)d_out;

    const int N = out_size;                       // == N from setup_inputs
    const int elems_per_block = 256 * 4;          // 1024 floats per block
    const int nblocks = (N + elems_per_block - 1) / elems_per_block;

    osc_kernel<<<nblocks, 256, 0, stream>>>(z_re, z_im, ph_re, ph_im, out, N);
}

// Round 3
// 26.866 us; speedup vs baseline: 1.1790x; 1.1790x over previous
//
#include <hip/hip_runtime.h>
#include <math.h>

// y[k] = Re( phase * z_c^k ),  z_c = z * tanh(|z|)/|z|
//      = r^k * (ph_re*cos(k*theta) - ph_im*sin(k*theta)),
//   r = tanh(|z|), theta = atan2(z_im, z_re).
// r^k underflows f32 by k ~ -90/ln(r) (~330 for |z|=1) -> the tail is exact
// zeros in the reference's cumprod. Fast path: one cmp + one nt 16B store.

typedef float f32x4 __attribute__((ext_vector_type(4)));

__global__ void __launch_bounds__(256)
osc_kernel(const float* __restrict__ z_re_p, const float* __restrict__ z_im_p,
           const float* __restrict__ ph_re_p, const float* __restrict__ ph_im_p,
           float* __restrict__ out, long long n4, long long N) {
    const float zr = *z_re_p;
    const float zi = *z_im_p;
    const float pr = *ph_re_p;
    const float pi = *ph_im_p;

    const float mag   = sqrtf(zr * zr + zi * zi);
    const float r     = tanhf(mag);          // constrained magnitude, < 1
    const float theta = atan2f(zi, zr);      // angle unchanged by constraint
    const float lr    = logf(r);             // < 0
    // k >= kcut  =>  k*lr < -90  =>  r^k < ~8e-40  => reference f32 value is 0.
    const float kcutf = (lr < 0.0f) ? (-90.0f / lr) : 3.4e38f;

    const f32x4 zero4 = {0.f, 0.f, 0.f, 0.f};
    const long long stride = (long long)gridDim.x * blockDim.x;
    f32x4* __restrict__ out4 = reinterpret_cast<f32x4*>(out);

    for (long long i4 = (long long)blockIdx.x * blockDim.x + threadIdx.x;
         i4 < n4; i4 += stride) {
        const long long k0 = i4 * 4;
        if ((float)k0 >= kcutf) {
            // entire float4 is in the zero tail (e decreases with k)
            __builtin_nontemporal_store(zero4, out4 + i4);
        } else {
            f32x4 v;
#pragma unroll
            for (int j = 0; j < 4; ++j) {
                const float k = (float)(k0 + j);
                const float e = k * lr;
                if (e < -90.0f) {
                    v[j] = 0.0f;
                } else {
                    const float rk = expf(e);
                    float s, c;
                    sincosf(k * theta, &s, &c);
                    v[j] = rk * (pr * c - pi * s);
                }
            }
            out4[i4] = v;
        }
    }

    // scalar tail if N not divisible by 4 (not the case for N=2^25, but safe)
    if (blockIdx.x == 0 && threadIdx.x == 0) {
        for (long long idx = n4 * 4; idx < N; ++idx) {
            const float k = (float)idx;
            const float e = k * lr;
            if (e < -90.0f) {
                out[idx] = 0.0f;
            } else {
                const float rk = expf(e);
                float s, c;
                sincosf(k * theta, &s, &c);
                out[idx] = rk * (pr * c - pi * s);
            }
        }
    }
}

extern "C" void kernel_launch(void* const* d_in, const int* in_sizes, int n_in,
                              void* d_out, int out_size, void* d_ws, size_t ws_size,
                              hipStream_t stream) {
    const float* z_re = (const float*)d_in[0];
    const float* z_im = (const float*)d_in[1];
    const float* ph_re = (const float*)d_in[2];
    const float* ph_im = (const float*)d_in[3];
    float* out = (float*)d_out;

    const long long N  = (long long)out_size;
    const long long n4 = N / 4;

    // memory-bound: ~2048 blocks + grid-stride (G11); 256 thr * 16 iters each
    long long want = (n4 + 255) / 256;
    const int nblocks = (int)((want < 2048) ? (want ? want : 1) : 2048);

    osc_kernel<<<nblocks, 256, 0, stream>>>(z_re, z_im, ph_re, ph_im, out, n4, N);
}

// Round 4
// 23.111 us; speedup vs baseline: 1.3705x; 1.1625x over previous
//
#include <hip/hip_runtime.h>
#include <math.h>

// y[k] = Re( phase * z_c^k ),  z_c = z * tanh(|z|)/|z|
//      = r^k * (ph_re*cos(k*theta) - ph_im*sin(k*theta)),
//   r = tanh(|z|), theta = atan2(z_im, z_re).
// r^k underflows f32 by k ~ -90/ln(r) (~330 for |z|=1) -> all but the first
// few hundred outputs are exact zeros in the reference cumprod.
//
// Structure: each block owns a contiguous 1024-float4 (16 KB) chunk.
// Zero-tail blocks (all but ~1) take a uniform branch to a pure 4x
// dwordx4 store path (fill-kernel shape). Only the head block computes.

typedef float f32x4 __attribute__((ext_vector_type(4)));

__global__ void __launch_bounds__(256)
osc_kernel(const float* __restrict__ z_re_p, const float* __restrict__ z_im_p,
           const float* __restrict__ ph_re_p, const float* __restrict__ ph_im_p,
           float* __restrict__ out, long long n4, long long N) {
    const float zr = *z_re_p;
    const float zi = *z_im_p;
    const float pr = *ph_re_p;
    const float pi = *ph_im_p;

    const float mag   = sqrtf(zr * zr + zi * zi);
    const float r     = tanhf(mag);          // constrained magnitude, < 1
    const float theta = atan2f(zi, zr);      // angle unchanged by constraint
    const float lr    = logf(r);             // < 0
    // k >= kcut  =>  k*lr < -90  =>  r^k < ~8e-40  => reference f32 value is 0.
    const float kcutf = (lr < 0.0f) ? (-90.0f / lr) : 3.4e38f;

    const long long blockBase = (long long)blockIdx.x * 1024;  // in float4 units
    const int tid = threadIdx.x;
    f32x4* __restrict__ out4 = reinterpret_cast<f32x4*>(out);

    const bool full    = (blockBase + 1024) <= n4;
    // smallest k in this block's chunk; e = k*lr decreases with k, so if the
    // first element underflows, the whole chunk is zero.
    const bool allzero = ((float)(blockBase * 4) >= kcutf);

    if (full && allzero) {
        // pure streaming-store path: 4 coalesced dwordx4 per thread
        const f32x4 z4 = {0.f, 0.f, 0.f, 0.f};
        f32x4* p = out4 + blockBase + tid;
        p[0]   = z4;
        p[256] = z4;
        p[512] = z4;
        p[768] = z4;
    } else {
#pragma unroll
        for (int u = 0; u < 4; ++u) {
            const long long i4 = blockBase + tid + (long long)u * 256;
            if (i4 >= n4) break;
            const long long k0 = i4 * 4;
            f32x4 v;
#pragma unroll
            for (int j = 0; j < 4; ++j) {
                const float k = (float)(k0 + j);
                const float e = k * lr;
                if (e < -90.0f) {
                    v[j] = 0.0f;
                } else {
                    const float rk = expf(e);
                    float s, c;
                    sincosf(k * theta, &s, &c);
                    v[j] = rk * (pr * c - pi * s);
                }
            }
            out4[i4] = v;
        }
        // scalar tail if N not divisible by 4 (not the case for N=2^25)
        if (blockIdx.x == 0 && tid == 0) {
            for (long long idx = n4 * 4; idx < N; ++idx) {
                const float k = (float)idx;
                const float e = k * lr;
                if (e < -90.0f) {
                    out[idx] = 0.0f;
                } else {
                    const float rk = expf(e);
                    float s, c;
                    sincosf(k * theta, &s, &c);
                    out[idx] = rk * (pr * c - pi * s);
                }
            }
        }
    }
}

extern "C" void kernel_launch(void* const* d_in, const int* in_sizes, int n_in,
                              void* d_out, int out_size, void* d_ws, size_t ws_size,
                              hipStream_t stream) {
    const float* z_re = (const float*)d_in[0];
    const float* z_im = (const float*)d_in[1];
    const float* ph_re = (const float*)d_in[2];
    const float* ph_im = (const float*)d_in[3];
    float* out = (float*)d_out;

    const long long N  = (long long)out_size;
    const long long n4 = N / 4;

    // one block per 1024 float4s (16 KB); exact cover, no grid-stride
    long long nb = (n4 + 1023) / 1024;
    if (nb < 1) nb = 1;
    osc_kernel<<<(int)nb, 256, 0, stream>>>(z_re, z_im, ph_re, ph_im, out, n4, N);
}